// Round 3
// baseline (762.317 us; speedup 1.0000x reference)
//
#include <hip/hip_runtime.h>

#define OBS_DIM 64
#define ACT_DIM 12
#define IN_DIM  76
#define HID     256
#define BATCH   1024
#define CAP     100000
#define NKT     64
#define NCHUNK  ((CAP + NKT - 1) / NKT)      /* 1563 */
#define ROWSPLIT 2
#define ROWS_PB (BATCH / ROWSPLIT)           /* 512 rows per block */
#define NRG     (ROWS_PB / 128)              /* 4 rowgroups */
#define CGRP    16
#define CPG     ((NCHUNK + CGRP - 1) / CGRP) /* 98 */
#define LOG2E   1.4426950408889634f
#define CHUNK_HALFS (NKT * HID)              /* 16384 halfs = 32 KB per chunk */

typedef __attribute__((ext_vector_type(8))) _Float16 f16x8;
typedef __attribute__((ext_vector_type(4))) _Float16 f16x4;
typedef __attribute__((ext_vector_type(4))) float    f32x4;

// ---- fused pre-pass: (blocks < NCHUNK) repack keys fp32->fp16 frag layout + n2;
// ---- (blocks >= NCHUNK) trunk: x@W + b, LayerNorm, tanh -> A (fp16)
__global__ __launch_bounds__(256) void np_pre(const float* __restrict__ obs,
                                              const float* __restrict__ act,
                                              const float* __restrict__ W,
                                              const float* __restrict__ bias,
                                              const float* __restrict__ gamma,
                                              const float* __restrict__ beta,
                                              const float* __restrict__ keys,
                                              _Float16* __restrict__ keys16,
                                              float* __restrict__ n2g,
                                              _Float16* __restrict__ A) {
    __shared__ float sh[256];
    const int t = threadIdx.x;
    if (blockIdx.x < NCHUNK) {
        // ---------- key repack ----------
        const int chunk = blockIdx.x;
        const int kb = chunk * NKT;
        const int keyl = t >> 2;
        const int key = kb + keyl;
        const int k0 = (t & 3) * 64;
        const bool ok = key < CAP;
        const float* src = keys + (size_t)key * HID + k0;
        _Float16* dst = keys16 + (size_t)chunk * CHUNK_HALFS;
        float sq = 0.f;
#pragma unroll
        for (int i = 0; i < 16; ++i) {
            float4 f = make_float4(0.f, 0.f, 0.f, 0.f);
            if (ok) f = ((const float4*)src)[i];
            sq = fmaf(f.x, f.x, sq); sq = fmaf(f.y, f.y, sq);
            sq = fmaf(f.z, f.z, sq); sq = fmaf(f.w, f.w, sq);
            const int k = k0 + i * 4;
            f16x4 hv = {(_Float16)f.x, (_Float16)f.y, (_Float16)f.z, (_Float16)f.w};
            // frag layout: halfs index = ((k>>3)*64 + keyl)*8 + (k&7)
            *(f16x4*)(dst + ((size_t)((k >> 3) * NKT + keyl) << 3) + (k & 7)) = hv;
        }
        sh[t] = sq;
        __syncthreads();
        if (t < NKT) {
            const float n = sh[4 * t] + sh[4 * t + 1] + sh[4 * t + 2] + sh[4 * t + 3];
            n2g[kb + t] = (kb + t < CAP) ? -n * LOG2E : -1e37f;  // pad -> logit -inf
        }
    } else {
        // ---------- trunk ----------
        const int row = blockIdx.x - NCHUNK;
        float* x = sh;          // [0..75]
        float* red = sh + 80;   // [80..87]
        if (t < OBS_DIM) x[t] = obs[row * OBS_DIM + t];
        else if (t < IN_DIM) x[t] = act[row * ACT_DIM + (t - OBS_DIM)];
        __syncthreads();
        float h = bias[t];
#pragma unroll
        for (int k = 0; k < IN_DIM; ++k) h = fmaf(x[k], W[k * HID + t], h);
        float s1 = h, s2 = h * h;
#pragma unroll
        for (int m = 1; m < 64; m <<= 1) { s1 += __shfl_xor(s1, m, 64); s2 += __shfl_xor(s2, m, 64); }
        const int wave = t >> 6;
        if ((t & 63) == 0) { red[wave] = s1; red[4 + wave] = s2; }
        __syncthreads();
        const float S1 = red[0] + red[1] + red[2] + red[3];
        const float S2 = red[4] + red[5] + red[6] + red[7];
        const float mu = S1 * (1.0f / 256.0f);
        const float var = S2 * (1.0f / 256.0f) - mu * mu;
        const float rs = rsqrtf(var + 1e-5f);
        const float g = (h - mu) * rs * gamma[t] + beta[t];
        const float e = exp2f(g * (2.0f * LOG2E));
        const float ph = 1.0f - 2.0f / (e + 1.0f);
        A[row * HID + t] = (_Float16)ph;
    }
}

// ------------- key-stationary fused GEMM + per-64-key-tile softmax -------------
// Keys arrive pre-converted/pre-swizzled in keys16 (frag layout); staging is pure
// global_load_lds DMA (no VGPR round-trip, no convert, no reduction). Live set
// ~116 VGPR -> (256,4) holds 4 blocks/CU with zero spill.
// grid = NCHUNK*2; block owns keys [chunk*64,+64), rows [half*512,+512).
__global__ __launch_bounds__(256, 4) void np_gemm(const _Float16* __restrict__ keys16,
                                                  const float* __restrict__ n2g,
                                                  const float* __restrict__ vals,
                                                  const _Float16* __restrict__ A,
                                                  float* __restrict__ pm,
                                                  float* __restrict__ pl,
                                                  float* __restrict__ pa) {
    const int chunk = blockIdx.x >> 1;
    const int half = blockIdx.x & 1;
    const int kb = chunk * NKT;
    const int t = threadIdx.x;
    const int lane = t & 63;
    const int wave = t >> 6;
    const int q = lane >> 4;      // quad within wave (k-chunk selector)
    const int rcol = lane & 15;   // row within 16-row tile (C column)

    __shared__ __align__(16) char Bt[32768];       // frag-layout key tile
    __shared__ __align__(16) float n2s[64];
    __shared__ __align__(16) float vv[64];

    // ---- async DMA: 32 KB keys16 chunk -> LDS (identity mapping) ----
    {
        const char* gsrc = (const char*)(keys16 + (size_t)chunk * CHUNK_HALFS) + wave * 1024 + lane * 16;
        char* ldst = Bt + wave * 1024;
#pragma unroll
        for (int j = 0; j < 8; ++j) {
            __builtin_amdgcn_global_load_lds(
                (const __attribute__((address_space(1))) void*)(gsrc + j * 4096),
                (__attribute__((address_space(3))) void*)(ldst + j * 4096), 16, 0, 0);
        }
        if (t < NKT) {
            n2s[t] = n2g[kb + t];
            vv[t] = (kb + t < CAP) ? vals[kb + t] : 0.f;
        }
    }

    const float C1 = 2.0f * LOG2E;

    // A fragments: 2 row-tiles x 8 ksteps (B-operand layout)
    f16x8 af[2][8];
#define LOADAF(RG) do {                                                               \
        const int rowbase_ = half * ROWS_PB + (RG) * 128 + wave * 32;                 \
        _Pragma("unroll")                                                             \
        for (int tb_ = 0; tb_ < 2; ++tb_) {                                           \
            const f16x8* ap_ = (const f16x8*)(A + (size_t)(rowbase_ + tb_ * 16 + rcol) * HID + q * 8); \
            _Pragma("unroll")                                                         \
            for (int s_ = 0; s_ < 8; ++s_) af[tb_][s_] = ap_[s_ * 4];                 \
        }                                                                             \
    } while (0)

    LOADAF(0);          // overlap A L2 latency with key DMA
    __syncthreads();    // drains vmcnt (key DMA + A loads)

#pragma unroll 1
    for (int rg = 0; rg < NRG; ++rg) {
        const int rowbase = half * ROWS_PB + rg * 128 + wave * 32;
        f32x4 acc[2][4];
#pragma unroll
        for (int tb = 0; tb < 2; ++tb)
#pragma unroll
            for (int c = 0; c < 4; ++c) acc[tb][c] = (f32x4){0.f, 0.f, 0.f, 0.f};

#pragma unroll
        for (int s = 0; s < 8; ++s) {
#pragma unroll
            for (int c = 0; c < 4; ++c) {
                const f16x8 bf = *(const f16x8*)(Bt + (((s * 4 + q) * 64 + c * 16 + rcol) << 4));
                // swapped operands: C[key][row]
                acc[0][c] = __builtin_amdgcn_mfma_f32_16x16x32_f16(bf, af[0][s], acc[0][c], 0, 0, 0);
                acc[1][c] = __builtin_amdgcn_mfma_f32_16x16x32_f16(bf, af[1][s], acc[1][c], 0, 0, 0);
            }
        }

        // prefetch next rowgroup's A while softmax VALU runs
        if (rg + 1 < NRG) LOADAF(rg + 1);

        // ---- in-lane softmax partials: lane holds keys {c*16 + q*4 + r} of one row ----
#pragma unroll
        for (int tb = 0; tb < 2; ++tb) {
#pragma unroll
            for (int c = 0; c < 4; ++c) {
                const f32x4 nn = *(const f32x4*)&n2s[c * 16 + q * 4];
#pragma unroll
                for (int r = 0; r < 4; ++r) acc[tb][c][r] = fmaf(acc[tb][c][r], C1, nn[r]);
            }
            float m0 = fmaxf(fmaxf(acc[tb][0][0], acc[tb][0][1]), fmaxf(acc[tb][0][2], acc[tb][0][3]));
            float m1 = fmaxf(fmaxf(acc[tb][1][0], acc[tb][1][1]), fmaxf(acc[tb][1][2], acc[tb][1][3]));
            float m2 = fmaxf(fmaxf(acc[tb][2][0], acc[tb][2][1]), fmaxf(acc[tb][2][2], acc[tb][2][3]));
            float m3 = fmaxf(fmaxf(acc[tb][3][0], acc[tb][3][1]), fmaxf(acc[tb][3][2], acc[tb][3][3]));
            float m = fmaxf(fmaxf(m0, m1), fmaxf(m2, m3));
            m = fmaxf(m, __shfl_xor(m, 16, 64));
            m = fmaxf(m, __shfl_xor(m, 32, 64));
            float lsum = 0.f, asum = 0.f;
#pragma unroll
            for (int c = 0; c < 4; ++c) {
                const f32x4 vl = *(const f32x4*)&vv[c * 16 + q * 4];
                const float w0 = exp2f(acc[tb][c][0] - m);
                const float w1 = exp2f(acc[tb][c][1] - m);
                const float w2 = exp2f(acc[tb][c][2] - m);
                const float w3 = exp2f(acc[tb][c][3] - m);
                lsum += (w0 + w1) + (w2 + w3);
                asum += fmaf(w0, vl[0], fmaf(w1, vl[1], fmaf(w2, vl[2], w3 * vl[3])));
            }
            lsum += __shfl_xor(lsum, 16, 64);
            lsum += __shfl_xor(lsum, 32, 64);
            asum += __shfl_xor(asum, 16, 64);
            asum += __shfl_xor(asum, 32, 64);
            if (lane < 16) {
                const int row = rowbase + tb * 16 + lane;
                const size_t idx = (size_t)chunk * BATCH + row;
                pm[idx] = m; pl[idx] = lsum; pa[idx] = asum;
            }
        }
    }
#undef LOADAF
}

// ------------- merge stage 1: 16 chunk-groups x 16 row-blocks -------------
__global__ __launch_bounds__(256) void np_merge1(const float* __restrict__ pm,
                                                 const float* __restrict__ pl,
                                                 const float* __restrict__ pa,
                                                 float* __restrict__ pm2,
                                                 float* __restrict__ pl2,
                                                 float* __restrict__ pa2) {
    const int rb = blockIdx.x & 15;
    const int cgB = blockIdx.x >> 4;
    const int t = threadIdx.x;
    const int row = rb * 64 + (t & 63);
    const int cg = t >> 6;
    const int cend = min((cgB + 1) * CPG, NCHUNK);
    float M = -3e38f, L = 0.f, Acc = 0.f;
    for (int c = cgB * CPG + cg; c < cend; c += 4) {
        const size_t idx = (size_t)c * BATCH + row;
        const float m = pm[idx], l = pl[idx], a = pa[idx];
        const float Mn = fmaxf(M, m);
        const float s0 = exp2f(M - Mn);
        const float s1 = exp2f(m - Mn);
        L = fmaf(L, s0, l * s1);
        Acc = fmaf(Acc, s0, a * s1);
        M = Mn;
    }
    __shared__ float sm[256], sl[256], sa[256];
    sm[t] = M; sl[t] = L; sa[t] = Acc;
    __syncthreads();
    if (t < 64) {
        const float M0 = sm[t], M1 = sm[t + 64], M2 = sm[t + 128], M3 = sm[t + 192];
        const float Mf = fmaxf(fmaxf(M0, M1), fmaxf(M2, M3));
        const float e0 = exp2f(M0 - Mf), e1 = exp2f(M1 - Mf), e2 = exp2f(M2 - Mf), e3 = exp2f(M3 - Mf);
        const float Lf = sl[t] * e0 + sl[t + 64] * e1 + sl[t + 128] * e2 + sl[t + 192] * e3;
        const float Af = sa[t] * e0 + sa[t + 64] * e1 + sa[t + 128] * e2 + sa[t + 192] * e3;
        const size_t o = (size_t)cgB * BATCH + rb * 64 + t;
        pm2[o] = Mf; pl2[o] = Lf; pa2[o] = Af;
    }
}

// ------------- merge stage 2: final 16-way merge, write q1==q2 -------------
__global__ __launch_bounds__(256) void np_merge2(const float* __restrict__ pm2,
                                                 const float* __restrict__ pl2,
                                                 const float* __restrict__ pa2,
                                                 float* __restrict__ out) {
    const int row = blockIdx.x * 256 + threadIdx.x;
    float M = -3e38f, L = 0.f, Acc = 0.f;
#pragma unroll 1
    for (int g = 0; g < CGRP; ++g) {
        const size_t idx = (size_t)g * BATCH + row;
        const float m = pm2[idx], l = pl2[idx], a = pa2[idx];
        const float Mn = fmaxf(M, m);
        const float s0 = exp2f(M - Mn);
        const float s1 = exp2f(m - Mn);
        L = fmaf(L, s0, l * s1);
        Acc = fmaf(Acc, s0, a * s1);
        M = Mn;
    }
    const float qv = Acc / L;
    out[row] = qv;
    out[BATCH + row] = qv;
}

extern "C" void kernel_launch(void* const* d_in, const int* in_sizes, int n_in,
                              void* d_out, int out_size, void* d_ws, size_t ws_size,
                              hipStream_t stream) {
    const float* obs   = (const float*)d_in[0];
    const float* act   = (const float*)d_in[1];
    const float* W     = (const float*)d_in[2];
    const float* bias  = (const float*)d_in[3];
    const float* gamma = (const float*)d_in[4];
    const float* beta  = (const float*)d_in[5];
    const float* keys  = (const float*)d_in[6];
    const float* vals  = (const float*)d_in[7];
    float* out = (float*)d_out;

    char* w = (char*)d_ws;
    _Float16* keys16 = (_Float16*)w;                       // 51.22 MB
    w += (size_t)NCHUNK * CHUNK_HALFS * sizeof(_Float16);
    float* n2g = (float*)w;                                // 400 KB
    w += (size_t)NCHUNK * NKT * sizeof(float);
    _Float16* A = (_Float16*)w;                            // 512 KB
    w += (size_t)BATCH * HID * sizeof(_Float16);
    float* pm = (float*)w;                                 // 3 x 6.4 MB
    float* pl = pm + (size_t)NCHUNK * BATCH;
    float* pa = pl + (size_t)NCHUNK * BATCH;
    float* pm2 = pa + (size_t)NCHUNK * BATCH;              // 3 x 64 KB
    float* pl2 = pm2 + (size_t)CGRP * BATCH;
    float* pa2 = pl2 + (size_t)CGRP * BATCH;

    np_pre<<<NCHUNK + BATCH, 256, 0, stream>>>(obs, act, W, bias, gamma, beta,
                                               keys, keys16, n2g, A);
    np_gemm<<<NCHUNK * ROWSPLIT, 256, 0, stream>>>(keys16, n2g, vals, A, pm, pl, pa);
    np_merge1<<<CGRP * 16, 256, 0, stream>>>(pm, pl, pa, pm2, pl2, pa2);
    np_merge2<<<BATCH / 256, 256, 0, stream>>>(pm2, pl2, pa2, out);
}

// Round 4
// 341.688 us; speedup vs baseline: 2.2310x; 2.2310x over previous
//
#include <hip/hip_runtime.h>

#define OBS_DIM 64
#define ACT_DIM 12
#define IN_DIM  76
#define HID     256
#define BATCH   1024
#define CAP     100000
#define NKT     64
#define NCHUNK  ((CAP + NKT - 1) / NKT)      /* 1563 */
#define CGRP    16
#define CPG     ((NCHUNK + CGRP - 1) / CGRP) /* 98 */
#define LOG2E   1.4426950408889634f

/* keys16 record: [0,32768) frag-layout fp16 keys; [32768,33024) n2 fp32[64];
   [33024,33280) padded vals fp32[64]; [33280,33792) pad (DMA'd, never read) */
#define REC_BYTES 33792
#define N2_OFF    32768

#define ROWT  64                              /* rows per gemm block */
#define NRT   (BATCH / ROWT)                  /* 16 row-tiles */
#define CBLK  128                             /* chunk-strided blocks per row-tile */

typedef __attribute__((ext_vector_type(8))) _Float16 f16x8;
typedef __attribute__((ext_vector_type(4))) _Float16 f16x4;
typedef __attribute__((ext_vector_type(4))) float    f32x4;

// ---- fused pre-pass: (blocks < NCHUNK) repack keys fp32->fp16 frag records;
// ---- (blocks >= NCHUNK) trunk: x@W + b, LayerNorm, tanh -> A (fp16)
__global__ __launch_bounds__(256) void np_pre(const float* __restrict__ obs,
                                              const float* __restrict__ act,
                                              const float* __restrict__ W,
                                              const float* __restrict__ bias,
                                              const float* __restrict__ gamma,
                                              const float* __restrict__ beta,
                                              const float* __restrict__ keys,
                                              const float* __restrict__ vals,
                                              char* __restrict__ keys16c,
                                              _Float16* __restrict__ A) {
    __shared__ float sh[256];
    const int t = threadIdx.x;
    if (blockIdx.x < NCHUNK) {
        // ---------- key repack + footer ----------
        const int chunk = blockIdx.x;
        const int kb = chunk * NKT;
        const int keyl = t >> 2;
        const int key = kb + keyl;
        const int k0 = (t & 3) * 64;
        const bool ok = key < CAP;
        const float* src = keys + (size_t)key * HID + k0;
        char* rec = keys16c + (size_t)chunk * REC_BYTES;
        _Float16* dst = (_Float16*)rec;
        float sq = 0.f;
#pragma unroll
        for (int i = 0; i < 16; ++i) {
            float4 f = make_float4(0.f, 0.f, 0.f, 0.f);
            if (ok) f = ((const float4*)src)[i];
            sq = fmaf(f.x, f.x, sq); sq = fmaf(f.y, f.y, sq);
            sq = fmaf(f.z, f.z, sq); sq = fmaf(f.w, f.w, sq);
            const int k = k0 + i * 4;
            f16x4 hv = {(_Float16)f.x, (_Float16)f.y, (_Float16)f.z, (_Float16)f.w};
            // frag layout: half index = ((k>>3)*64 + keyl)*8 + (k&7)
            *(f16x4*)(dst + ((size_t)((k >> 3) * NKT + keyl) << 3) + (k & 7)) = hv;
        }
        sh[t] = sq;
        __syncthreads();
        if (t < NKT) {
            const float n = sh[4 * t] + sh[4 * t + 1] + sh[4 * t + 2] + sh[4 * t + 3];
            float* foot = (float*)(rec + N2_OFF);
            const bool okk = (kb + t) < CAP;
            foot[t] = okk ? -n * LOG2E : -1e37f;        // pad -> logit -inf
            foot[64 + t] = okk ? vals[kb + t] : 0.f;    // pad -> value 0 (no NaN)
        }
    } else {
        // ---------- trunk ----------
        const int row = blockIdx.x - NCHUNK;
        float* x = sh;          // [0..75]
        float* red = sh + 80;   // [80..87]
        if (t < OBS_DIM) x[t] = obs[row * OBS_DIM + t];
        else if (t < IN_DIM) x[t] = act[row * ACT_DIM + (t - OBS_DIM)];
        __syncthreads();
        float h = bias[t];
#pragma unroll
        for (int k = 0; k < IN_DIM; ++k) h = fmaf(x[k], W[k * HID + t], h);
        float s1 = h, s2 = h * h;
#pragma unroll
        for (int m = 1; m < 64; m <<= 1) { s1 += __shfl_xor(s1, m, 64); s2 += __shfl_xor(s2, m, 64); }
        const int wave = t >> 6;
        if ((t & 63) == 0) { red[wave] = s1; red[4 + wave] = s2; }
        __syncthreads();
        const float S1 = red[0] + red[1] + red[2] + red[3];
        const float S2 = red[4] + red[5] + red[6] + red[7];
        const float mu = S1 * (1.0f / 256.0f);
        const float var = S2 * (1.0f / 256.0f) - mu * mu;
        const float rs = rsqrtf(var + 1e-5f);
        const float g = (h - mu) * rs * gamma[t] + beta[t];
        const float e = exp2f(g * (2.0f * LOG2E));
        const float ph = 1.0f - 2.0f / (e + 1.0f);
        A[row * HID + t] = (_Float16)ph;
    }
}

// ------------- A-stationary fused GEMM + per-64-key-tile softmax -------------
// Block owns 64 rows (wave owns 16); af[8] (32 VGPR) loaded ONCE. Key chunks
// stream through double-buffered LDS via global_load_lds DMA (issue next before
// computing current). Peak live ~80 VGPR -> no spill (rounds 1/3 lesson: never
// force 4 waves/EU; rowgroup-looped af[2][8] spills at any bound).
// grid = NRT*CBLK = 2048; block (rt,cb) does chunks c = cb, cb+128, ... < NCHUNK.
// Sharers of a chunk are 128 apart in blockIdx => same XCD under %8 round-robin.
__global__ __launch_bounds__(256, 2) void np_gemm(const char* __restrict__ keys16c,
                                                  const _Float16* __restrict__ A,
                                                  float* __restrict__ pm,
                                                  float* __restrict__ pl,
                                                  float* __restrict__ pa) {
    const int rt = blockIdx.x / CBLK;
    const int cb = blockIdx.x % CBLK;
    const int t = threadIdx.x;
    const int lane = t & 63;
    const int wave = t >> 6;
    const int q = lane >> 4;      // quad within wave (k-chunk selector)
    const int rcol = lane & 15;   // row within the wave's 16-row tile

    __shared__ __align__(16) char buf[2][REC_BYTES];  // 67584 B -> 2 blocks/CU

    const float C1 = 2.0f * LOG2E;
    const int rowbase = rt * ROWT + wave * 16;

#define DMAISSUE(C, IB) do {                                                          \
        const char* rec_ = keys16c + (size_t)(C) * REC_BYTES;                         \
        const char* gsrc_ = rec_ + wave * 1024 + lane * 16;                           \
        char* ldst_ = &buf[IB][0] + wave * 1024;                                      \
        _Pragma("unroll")                                                             \
        for (int j_ = 0; j_ < 8; ++j_) {                                              \
            __builtin_amdgcn_global_load_lds(                                         \
                (const __attribute__((address_space(1))) void*)(gsrc_ + j_ * 4096),   \
                (__attribute__((address_space(3))) void*)(ldst_ + j_ * 4096), 16, 0, 0); \
        }                                                                             \
        if (wave == 0) {                                                              \
            __builtin_amdgcn_global_load_lds(                                         \
                (const __attribute__((address_space(1))) void*)(rec_ + N2_OFF + lane * 16), \
                (__attribute__((address_space(3))) void*)(&buf[IB][0] + N2_OFF), 16, 0, 0); \
        }                                                                             \
    } while (0)

    // ---- prologue: DMA first chunk, load stationary A fragments ----
    int c = cb;
    DMAISSUE(c, 0);
    f16x8 af[8];
    {
        const f16x8* ap = (const f16x8*)(A + (size_t)(rowbase + rcol) * HID + q * 8);
#pragma unroll
        for (int s = 0; s < 8; ++s) af[s] = ap[s * 4];
    }
    __syncthreads();   // drains vmcnt: chunk0 DMA + af loads

    int ib = 0;
#pragma unroll 1
    for (; c < NCHUNK; ) {
        const int cn = c + CBLK;
        if (cn < NCHUNK) DMAISSUE(cn, ib ^ 1);   // prefetch next chunk

        const _Float16* bt16 = (const _Float16*)&buf[ib][0];
        f32x4 acc[4];
#pragma unroll
        for (int cc = 0; cc < 4; ++cc) acc[cc] = (f32x4){0.f, 0.f, 0.f, 0.f};
#pragma unroll
        for (int s = 0; s < 8; ++s) {
#pragma unroll
            for (int cc = 0; cc < 4; ++cc) {
                const f16x8 bf = *(const f16x8*)(bt16 + (((s * 4 + q) * 64 + cc * 16 + rcol) << 3));
                // swapped operands: C[key][row]
                acc[cc] = __builtin_amdgcn_mfma_f32_16x16x32_f16(bf, af[s], acc[cc], 0, 0, 0);
            }
        }

        // ---- in-lane softmax partials: lane holds keys {cc*16 + q*4 + r} of one row ----
        const float* n2s = (const float*)(&buf[ib][0] + N2_OFF);
        const float* vvs = n2s + 64;
#pragma unroll
        for (int cc = 0; cc < 4; ++cc) {
            const f32x4 nn = *(const f32x4*)&n2s[cc * 16 + q * 4];
#pragma unroll
            for (int r = 0; r < 4; ++r) acc[cc][r] = fmaf(acc[cc][r], C1, nn[r]);
        }
        float m0 = fmaxf(fmaxf(acc[0][0], acc[0][1]), fmaxf(acc[0][2], acc[0][3]));
        float m1 = fmaxf(fmaxf(acc[1][0], acc[1][1]), fmaxf(acc[1][2], acc[1][3]));
        float m2 = fmaxf(fmaxf(acc[2][0], acc[2][1]), fmaxf(acc[2][2], acc[2][3]));
        float m3 = fmaxf(fmaxf(acc[3][0], acc[3][1]), fmaxf(acc[3][2], acc[3][3]));
        float m = fmaxf(fmaxf(m0, m1), fmaxf(m2, m3));
        m = fmaxf(m, __shfl_xor(m, 16, 64));
        m = fmaxf(m, __shfl_xor(m, 32, 64));
        float lsum = 0.f, asum = 0.f;
#pragma unroll
        for (int cc = 0; cc < 4; ++cc) {
            const f32x4 vl = *(const f32x4*)&vvs[cc * 16 + q * 4];
            const float w0 = exp2f(acc[cc][0] - m);
            const float w1 = exp2f(acc[cc][1] - m);
            const float w2 = exp2f(acc[cc][2] - m);
            const float w3 = exp2f(acc[cc][3] - m);
            lsum += (w0 + w1) + (w2 + w3);
            asum += fmaf(w0, vl[0], fmaf(w1, vl[1], fmaf(w2, vl[2], w3 * vl[3])));
        }
        lsum += __shfl_xor(lsum, 16, 64);
        lsum += __shfl_xor(lsum, 32, 64);
        asum += __shfl_xor(asum, 16, 64);
        asum += __shfl_xor(asum, 32, 64);
        if (lane < 16) {
            const int row = rowbase + lane;
            const size_t idx = (size_t)c * BATCH + row;
            pm[idx] = m; pl[idx] = lsum; pa[idx] = asum;
        }

        __syncthreads();   // next DMA drained + all reads of buf[ib] done
        c = cn; ib ^= 1;
    }
#undef DMAISSUE
}

// ------------- merge stage 1: 16 chunk-groups x 16 row-blocks -------------
__global__ __launch_bounds__(256) void np_merge1(const float* __restrict__ pm,
                                                 const float* __restrict__ pl,
                                                 const float* __restrict__ pa,
                                                 float* __restrict__ pm2,
                                                 float* __restrict__ pl2,
                                                 float* __restrict__ pa2) {
    const int rb = blockIdx.x & 15;
    const int cgB = blockIdx.x >> 4;
    const int t = threadIdx.x;
    const int row = rb * 64 + (t & 63);
    const int cg = t >> 6;
    const int cend = min((cgB + 1) * CPG, NCHUNK);
    float M = -3e38f, L = 0.f, Acc = 0.f;
    for (int c = cgB * CPG + cg; c < cend; c += 4) {
        const size_t idx = (size_t)c * BATCH + row;
        const float m = pm[idx], l = pl[idx], a = pa[idx];
        const float Mn = fmaxf(M, m);
        const float s0 = exp2f(M - Mn);
        const float s1 = exp2f(m - Mn);
        L = fmaf(L, s0, l * s1);
        Acc = fmaf(Acc, s0, a * s1);
        M = Mn;
    }
    __shared__ float sm[256], sl[256], sa[256];
    sm[t] = M; sl[t] = L; sa[t] = Acc;
    __syncthreads();
    if (t < 64) {
        const float M0 = sm[t], M1 = sm[t + 64], M2 = sm[t + 128], M3 = sm[t + 192];
        const float Mf = fmaxf(fmaxf(M0, M1), fmaxf(M2, M3));
        const float e0 = exp2f(M0 - Mf), e1 = exp2f(M1 - Mf), e2 = exp2f(M2 - Mf), e3 = exp2f(M3 - Mf);
        const float Lf = sl[t] * e0 + sl[t + 64] * e1 + sl[t + 128] * e2 + sl[t + 192] * e3;
        const float Af = sa[t] * e0 + sa[t + 64] * e1 + sa[t + 128] * e2 + sa[t + 192] * e3;
        const size_t o = (size_t)cgB * BATCH + rb * 64 + t;
        pm2[o] = Mf; pl2[o] = Lf; pa2[o] = Af;
    }
}

// ------------- merge stage 2: final 16-way merge, write q1==q2 -------------
__global__ __launch_bounds__(256) void np_merge2(const float* __restrict__ pm2,
                                                 const float* __restrict__ pl2,
                                                 const float* __restrict__ pa2,
                                                 float* __restrict__ out) {
    const int row = blockIdx.x * 256 + threadIdx.x;
    float M = -3e38f, L = 0.f, Acc = 0.f;
#pragma unroll 1
    for (int g = 0; g < CGRP; ++g) {
        const size_t idx = (size_t)g * BATCH + row;
        const float m = pm2[idx], l = pl2[idx], a = pa2[idx];
        const float Mn = fmaxf(M, m);
        const float s0 = exp2f(M - Mn);
        const float s1 = exp2f(m - Mn);
        L = fmaf(L, s0, l * s1);
        Acc = fmaf(Acc, s0, a * s1);
        M = Mn;
    }
    const float qv = Acc / L;
    out[row] = qv;
    out[BATCH + row] = qv;
}

extern "C" void kernel_launch(void* const* d_in, const int* in_sizes, int n_in,
                              void* d_out, int out_size, void* d_ws, size_t ws_size,
                              hipStream_t stream) {
    const float* obs   = (const float*)d_in[0];
    const float* act   = (const float*)d_in[1];
    const float* W     = (const float*)d_in[2];
    const float* bias  = (const float*)d_in[3];
    const float* gamma = (const float*)d_in[4];
    const float* beta  = (const float*)d_in[5];
    const float* keys  = (const float*)d_in[6];
    const float* vals  = (const float*)d_in[7];
    float* out = (float*)d_out;

    char* w = (char*)d_ws;
    char* keys16c = w;                                     // 52.8 MB records
    w += (size_t)NCHUNK * REC_BYTES;
    _Float16* A = (_Float16*)w;                            // 512 KB
    w += (size_t)BATCH * HID * sizeof(_Float16);
    float* pm = (float*)w;                                 // 3 x 6.4 MB
    float* pl = pm + (size_t)NCHUNK * BATCH;
    float* pa = pl + (size_t)NCHUNK * BATCH;
    float* pm2 = pa + (size_t)NCHUNK * BATCH;              // 3 x 64 KB
    float* pl2 = pm2 + (size_t)CGRP * BATCH;
    float* pa2 = pl2 + (size_t)CGRP * BATCH;

    np_pre<<<NCHUNK + BATCH, 256, 0, stream>>>(obs, act, W, bias, gamma, beta,
                                               keys, vals, keys16c, A);
    np_gemm<<<NRT * CBLK, 256, 0, stream>>>(keys16c, A, pm, pl, pa);
    np_merge1<<<CGRP * 16, 256, 0, stream>>>(pm, pl, pa, pm2, pl2, pa2);
    np_merge2<<<BATCH / 256, 256, 0, stream>>>(pm2, pl2, pa2, out);
}

// Round 5
// 271.900 us; speedup vs baseline: 2.8037x; 1.2567x over previous
//
#include <hip/hip_runtime.h>

#define OBS_DIM 64
#define ACT_DIM 12
#define IN_DIM  76
#define HID     256
#define BATCH   1024
#define CAP     100000
#define NKT     64
#define NCHUNK  ((CAP + NKT - 1) / NKT)      /* 1563 */
#define LOG2E   1.4426950408889634f

/* keys16 record: [0,32768) frag-layout fp16 keys; [32768,33024) n2 fp32[64];
   [33024,33280) padded vals fp32[64]; [33280,33792) pad (DMA'd, never read) */
#define REC_BYTES 33792
#define N2_OFF    32768

#define ROWT  128                             /* rows per gemm block (wave: 32) */
#define NRT   (BATCH / ROWT)                  /* 8 row-tiles */
#define CBLK  128                             /* chunk-strided blocks per row-tile */

typedef __attribute__((ext_vector_type(8))) _Float16 f16x8;
typedef __attribute__((ext_vector_type(4))) _Float16 f16x4;
typedef __attribute__((ext_vector_type(4))) float    f32x4;

// ---- fused pre-pass: (blocks < NCHUNK) repack keys fp32->fp16 frag records
// ---- via LDS (coalesced 16B global stores); (blocks >= NCHUNK) trunk.
__global__ __launch_bounds__(256) void np_pre(const float* __restrict__ obs,
                                              const float* __restrict__ act,
                                              const float* __restrict__ W,
                                              const float* __restrict__ bias,
                                              const float* __restrict__ gamma,
                                              const float* __restrict__ beta,
                                              const float* __restrict__ keys,
                                              const float* __restrict__ vals,
                                              char* __restrict__ keys16c,
                                              _Float16* __restrict__ A) {
    __shared__ __align__(16) _Float16 lbuf[16384];  // 32 KB staging (repack only)
    __shared__ float shred[256];
    const int t = threadIdx.x;
    if (blockIdx.x < NCHUNK) {
        // ---------- key repack: global(coalesced) -> LDS(frag scatter) -> global(coalesced) ----------
        const int chunk = blockIdx.x;
        const int kb = chunk * NKT;
        const int keyl = t >> 2;
        const int key = kb + keyl;
        const int seg = t & 3;
        const int k0 = seg * 64;
        const bool ok = key < CAP;
        const float* src = keys + (size_t)key * HID + k0;
        char* rec = keys16c + (size_t)chunk * REC_BYTES;
        float sq = 0.f;
#pragma unroll
        for (int i = 0; i < 16; ++i) {
            float4 f = make_float4(0.f, 0.f, 0.f, 0.f);
            if (ok) f = ((const float4*)src)[i];
            sq = fmaf(f.x, f.x, sq); sq = fmaf(f.y, f.y, sq);
            sq = fmaf(f.z, f.z, sq); sq = fmaf(f.w, f.w, sq);
            const int k = k0 + i * 4;
            f16x4 hv = {(_Float16)f.x, (_Float16)f.y, (_Float16)f.z, (_Float16)f.w};
            // frag layout: half index = ((k>>3)*64 + keyl)*8 + (k&7)
            *(f16x4*)(&lbuf[(((k >> 3) * NKT + keyl) << 3) + (k & 7)]) = hv;
        }
        shred[t] = sq;
        __syncthreads();
        // coalesced writeback: 8 x 16B cells per thread, lane-consecutive
#pragma unroll
        for (int j = 0; j < 8; ++j) {
            const int cell = j * 256 + t;
            *(f16x8*)(rec + (size_t)cell * 16) = *(const f16x8*)&lbuf[cell << 3];
        }
        if (t < NKT) {
            const float n = shred[4 * t] + shred[4 * t + 1] + shred[4 * t + 2] + shred[4 * t + 3];
            float* foot = (float*)(rec + N2_OFF);
            const bool okk = (kb + t) < CAP;
            foot[t] = okk ? -n * LOG2E : -1e37f;        // pad -> logit -inf
            foot[64 + t] = okk ? vals[kb + t] : 0.f;    // pad -> value 0 (no NaN)
        }
    } else {
        // ---------- trunk ----------
        const int row = blockIdx.x - NCHUNK;
        float* x = shred;          // [0..75]
        float* red = shred + 80;   // [80..87]
        if (t < OBS_DIM) x[t] = obs[row * OBS_DIM + t];
        else if (t < IN_DIM) x[t] = act[row * ACT_DIM + (t - OBS_DIM)];
        __syncthreads();
        float h = bias[t];
#pragma unroll
        for (int k = 0; k < IN_DIM; ++k) h = fmaf(x[k], W[k * HID + t], h);
        float s1 = h, s2 = h * h;
#pragma unroll
        for (int m = 1; m < 64; m <<= 1) { s1 += __shfl_xor(s1, m, 64); s2 += __shfl_xor(s2, m, 64); }
        const int wave = t >> 6;
        if ((t & 63) == 0) { red[wave] = s1; red[4 + wave] = s2; }
        __syncthreads();
        const float S1 = red[0] + red[1] + red[2] + red[3];
        const float S2 = red[4] + red[5] + red[6] + red[7];
        const float mu = S1 * (1.0f / 256.0f);
        const float var = S2 * (1.0f / 256.0f) - mu * mu;
        const float rs = rsqrtf(var + 1e-5f);
        const float g = (h - mu) * rs * gamma[t] + beta[t];
        const float e = exp2f(g * (2.0f * LOG2E));
        const float ph = 1.0f - 2.0f / (e + 1.0f);
        A[row * HID + t] = (_Float16)ph;
    }
}

// ------------- A-stationary fused GEMM + ONLINE softmax over chunks -------------
// Wave owns 32 rows (2 row-tiles): each LDS key fragment read feeds 2 MFMAs,
// halving LDS-read traffic (round-4 bottleneck: 3.2 GB LDS reads = 46us floor).
// Online (M,L,A) kept in registers across ~12 chunks; ONE partial per row per
// block at the end (partials 1563->128 per row). LDS 66KB caps occupancy at
// 2 blocks/CU, so the allocator has no higher-occupancy target to spill for.
// grid = NRT*CBLK = 1024; block (rt,cb) does chunks c = cb, cb+128, ... < NCHUNK.
// Sharers of a chunk are 128 apart in blockIdx => same XCD under %8 round-robin.
__global__ __launch_bounds__(256, 2) void np_gemm(const char* __restrict__ keys16c,
                                                  const _Float16* __restrict__ A,
                                                  float* __restrict__ pm,
                                                  float* __restrict__ pl,
                                                  float* __restrict__ pa) {
    const int rt = blockIdx.x / CBLK;
    const int cb = blockIdx.x % CBLK;
    const int t = threadIdx.x;
    const int lane = t & 63;
    const int wave = t >> 6;
    const int q = lane >> 4;      // quad within wave (k-chunk selector)
    const int rcol = lane & 15;   // row within a 16-row tile

    __shared__ __align__(16) char buf[2][REC_BYTES];  // 67584 B -> 2 blocks/CU

    const float C1 = 2.0f * LOG2E;
    const int rowbase = rt * ROWT + wave * 32;

#define DMAISSUE(C, IB) do {                                                          \
        const char* rec_ = keys16c + (size_t)(C) * REC_BYTES;                         \
        const char* gsrc_ = rec_ + wave * 1024 + lane * 16;                           \
        char* ldst_ = &buf[IB][0] + wave * 1024;                                      \
        _Pragma("unroll")                                                             \
        for (int j_ = 0; j_ < 8; ++j_) {                                              \
            __builtin_amdgcn_global_load_lds(                                         \
                (const __attribute__((address_space(1))) void*)(gsrc_ + j_ * 4096),   \
                (__attribute__((address_space(3))) void*)(ldst_ + j_ * 4096), 16, 0, 0); \
        }                                                                             \
        if (wave == 0) {                                                              \
            __builtin_amdgcn_global_load_lds(                                         \
                (const __attribute__((address_space(1))) void*)(rec_ + N2_OFF + lane * 16), \
                (__attribute__((address_space(3))) void*)(&buf[IB][0] + N2_OFF), 16, 0, 0); \
        }                                                                             \
    } while (0)

    // ---- prologue: DMA first chunk, load stationary A fragments (2 row-tiles) ----
    int c = cb;
    DMAISSUE(c, 0);
    f16x8 af[2][8];
#pragma unroll
    for (int tb = 0; tb < 2; ++tb) {
        const f16x8* ap = (const f16x8*)(A + (size_t)(rowbase + tb * 16 + rcol) * HID + q * 8);
#pragma unroll
        for (int s = 0; s < 8; ++s) af[tb][s] = ap[s * 4];
    }
    // online softmax state per row-tile
    float M[2] = {-3e38f, -3e38f};
    float Lr[2] = {0.f, 0.f};
    float Ar[2] = {0.f, 0.f};
    __syncthreads();   // drains vmcnt: chunk0 DMA + af loads

    int ib = 0;
#pragma unroll 1
    for (; c < NCHUNK; ) {
        const int cn = c + CBLK;
        if (cn < NCHUNK) DMAISSUE(cn, ib ^ 1);   // prefetch next chunk

        const _Float16* bt16 = (const _Float16*)&buf[ib][0];
        f32x4 acc[2][4];
#pragma unroll
        for (int tb = 0; tb < 2; ++tb)
#pragma unroll
            for (int cc = 0; cc < 4; ++cc) acc[tb][cc] = (f32x4){0.f, 0.f, 0.f, 0.f};
#pragma unroll
        for (int s = 0; s < 8; ++s) {
#pragma unroll
            for (int cc = 0; cc < 4; ++cc) {
                const f16x8 bf = *(const f16x8*)(bt16 + (((s * 4 + q) * 64 + cc * 16 + rcol) << 3));
                // swapped operands: C[key][row]; one bf read feeds both row-tiles
                acc[0][cc] = __builtin_amdgcn_mfma_f32_16x16x32_f16(bf, af[0][s], acc[0][cc], 0, 0, 0);
                acc[1][cc] = __builtin_amdgcn_mfma_f32_16x16x32_f16(bf, af[1][s], acc[1][cc], 0, 0, 0);
            }
        }

        // ---- per-chunk ONLINE update (lane-local; lane holds 16 keys of one row) ----
        const float* n2s = (const float*)(&buf[ib][0] + N2_OFF);
        const float* vvs = n2s + 64;
#pragma unroll
        for (int tb = 0; tb < 2; ++tb) {
#pragma unroll
            for (int cc = 0; cc < 4; ++cc) {
                const f32x4 nn = *(const f32x4*)&n2s[cc * 16 + q * 4];
#pragma unroll
                for (int r = 0; r < 4; ++r) acc[tb][cc][r] = fmaf(acc[tb][cc][r], C1, nn[r]);
            }
            const float p0 = fmaxf(fmaxf(acc[tb][0][0], acc[tb][0][1]), fmaxf(acc[tb][0][2], acc[tb][0][3]));
            const float p1 = fmaxf(fmaxf(acc[tb][1][0], acc[tb][1][1]), fmaxf(acc[tb][1][2], acc[tb][1][3]));
            const float p2 = fmaxf(fmaxf(acc[tb][2][0], acc[tb][2][1]), fmaxf(acc[tb][2][2], acc[tb][2][3]));
            const float p3 = fmaxf(fmaxf(acc[tb][3][0], acc[tb][3][1]), fmaxf(acc[tb][3][2], acc[tb][3][3]));
            const float pmax = fmaxf(fmaxf(p0, p1), fmaxf(p2, p3));
            const float Mn = fmaxf(M[tb], pmax);
            const float sc = exp2f(M[tb] - Mn);   // first chunk: exp2(-inf)=0, L=A=0 anyway
            float ls = 0.f, as = 0.f;
#pragma unroll
            for (int cc = 0; cc < 4; ++cc) {
                const f32x4 vl = *(const f32x4*)&vvs[cc * 16 + q * 4];
                const float w0 = exp2f(acc[tb][cc][0] - Mn);
                const float w1 = exp2f(acc[tb][cc][1] - Mn);
                const float w2 = exp2f(acc[tb][cc][2] - Mn);
                const float w3 = exp2f(acc[tb][cc][3] - Mn);
                ls += (w0 + w1) + (w2 + w3);
                as += fmaf(w0, vl[0], fmaf(w1, vl[1], fmaf(w2, vl[2], w3 * vl[3])));
            }
            Lr[tb] = fmaf(Lr[tb], sc, ls);
            Ar[tb] = fmaf(Ar[tb], sc, as);
            M[tb] = Mn;
        }

        __syncthreads();   // next DMA drained + all reads of buf[ib] done
        c = cn; ib ^= 1;
    }
#undef DMAISSUE

    // ---- epilogue: merge across the 4 q-lanes of each row, write one partial ----
#pragma unroll
    for (int tb = 0; tb < 2; ++tb) {
        float m = M[tb], l = Lr[tb], a = Ar[tb];
#pragma unroll
        for (int sh = 16; sh < 64; sh <<= 1) {
            const float mo = __shfl_xor(m, sh, 64);
            const float lo = __shfl_xor(l, sh, 64);
            const float ao = __shfl_xor(a, sh, 64);
            const float mn = fmaxf(m, mo);
            const float s0 = exp2f(m - mn);
            const float s1 = exp2f(mo - mn);
            l = fmaf(l, s0, lo * s1);
            a = fmaf(a, s0, ao * s1);
            m = mn;
        }
        if (lane < 16) {
            const int row = rowbase + tb * 16 + lane;
            const size_t idx = (size_t)cb * BATCH + row;
            pm[idx] = m; pl[idx] = l; pa[idx] = a;
        }
    }
}

// ------------- single merge: 128-way per row, write q1==q2 -------------
__global__ __launch_bounds__(256) void np_merge(const float* __restrict__ pm,
                                                const float* __restrict__ pl,
                                                const float* __restrict__ pa,
                                                float* __restrict__ out) {
    const int t = threadIdx.x;
    const int row = blockIdx.x * 64 + (t & 63);
    const int cg = t >> 6;
    float M = -3e38f, L = 0.f, Acc = 0.f;
#pragma unroll 1
    for (int cb = cg; cb < CBLK; cb += 4) {
        const size_t idx = (size_t)cb * BATCH + row;
        const float m = pm[idx], l = pl[idx], a = pa[idx];
        const float Mn = fmaxf(M, m);
        const float s0 = exp2f(M - Mn);
        const float s1 = exp2f(m - Mn);
        L = fmaf(L, s0, l * s1);
        Acc = fmaf(Acc, s0, a * s1);
        M = Mn;
    }
    __shared__ float sm[256], sl[256], sa[256];
    sm[t] = M; sl[t] = L; sa[t] = Acc;
    __syncthreads();
    if (t < 64) {
        const float M0 = sm[t], M1 = sm[t + 64], M2 = sm[t + 128], M3 = sm[t + 192];
        const float Mf = fmaxf(fmaxf(M0, M1), fmaxf(M2, M3));
        const float e0 = exp2f(M0 - Mf), e1 = exp2f(M1 - Mf), e2 = exp2f(M2 - Mf), e3 = exp2f(M3 - Mf);
        const float Lf = sl[t] * e0 + sl[t + 64] * e1 + sl[t + 128] * e2 + sl[t + 192] * e3;
        const float Af = sa[t] * e0 + sa[t + 64] * e1 + sa[t + 128] * e2 + sa[t + 192] * e3;
        const float qv = Af / Lf;
        const int r = blockIdx.x * 64 + t;
        out[r] = qv;
        out[BATCH + r] = qv;
    }
}

extern "C" void kernel_launch(void* const* d_in, const int* in_sizes, int n_in,
                              void* d_out, int out_size, void* d_ws, size_t ws_size,
                              hipStream_t stream) {
    const float* obs   = (const float*)d_in[0];
    const float* act   = (const float*)d_in[1];
    const float* W     = (const float*)d_in[2];
    const float* bias  = (const float*)d_in[3];
    const float* gamma = (const float*)d_in[4];
    const float* beta  = (const float*)d_in[5];
    const float* keys  = (const float*)d_in[6];
    const float* vals  = (const float*)d_in[7];
    float* out = (float*)d_out;

    char* w = (char*)d_ws;
    char* keys16c = w;                                     // 52.8 MB records
    w += (size_t)NCHUNK * REC_BYTES;
    _Float16* A = (_Float16*)w;                            // 512 KB
    w += (size_t)BATCH * HID * sizeof(_Float16);
    float* pm = (float*)w;                                 // 3 x 512 KB
    float* pl = pm + (size_t)CBLK * BATCH;
    float* pa = pl + (size_t)CBLK * BATCH;

    np_pre<<<NCHUNK + BATCH, 256, 0, stream>>>(obs, act, W, bias, gamma, beta,
                                               keys, vals, keys16c, A);
    np_gemm<<<NRT * CBLK, 256, 0, stream>>>(keys16c, A, pm, pl, pa);
    np_merge<<<BATCH / 64, 256, 0, stream>>>(pm, pl, pa, out);
}